// Round 1
// baseline (5639.311 us; speedup 1.0000x reference)
//
#include <hip/hip_runtime.h>
#include <math.h>

#define KNN 16

// ---------------------------------------------------------------------------
// stem: F0[b,o,n] = stem_w[o,:] . xyz[b,:,n] + stem_b[o]   (B=2, C=8, N=8192)
// ---------------------------------------------------------------------------
__global__ __launch_bounds__(256) void stem_kernel(const float* __restrict__ xyz,
    const float* __restrict__ w, const float* __restrict__ bias,
    float* __restrict__ F0, int N){
  int id = blockIdx.x*256 + threadIdx.x;          // B*N
  int n = id % N; int b = id / N;
  float x = xyz[((size_t)b*3+0)*N+n];
  float y = xyz[((size_t)b*3+1)*N+n];
  float z = xyz[((size_t)b*3+2)*N+n];
  #pragma unroll
  for (int o=0;o<8;o++){
    float v = fmaf(w[o*3+0],x, fmaf(w[o*3+1],y, fmaf(w[o*3+2],z, bias[o])));
    F0[((size_t)b*8+o)*N+n] = v;
  }
}

// ---------------------------------------------------------------------------
// KNN: per-thread top-16 (smallest d), split over gridDim.y candidate ranges.
// Distance mirrors reference: (qq + pp) - 2*dot, all non-contracted IEEE ops.
// Selection set == stable top_k set (ties at boundary keep earlier index,
// since later-equal candidates are rejected by strict <).
// ---------------------------------------------------------------------------
__global__ __launch_bounds__(256) void knn_kernel(
    const float* __restrict__ Pq, const float* __restrict__ Pp,
    float* __restrict__ part_d, int* __restrict__ part_i,
    int Nq, int Np, int CAND){
  __shared__ float4 tile[256];
  int qg = blockIdx.x*256 + threadIdx.x;
  int b  = qg / Nq, qn = qg % Nq;
  int s  = blockIdx.y;
  const float* Pqb = Pq + (size_t)b*3*Nq;
  const float* Ppb = Pp + (size_t)b*3*Np;
  float qx = Pqb[qn], qy = Pqb[Nq+qn], qz = Pqb[2*Nq+qn];
  float qq = __fadd_rn(__fadd_rn(__fmul_rn(qx,qx),__fmul_rn(qy,qy)),__fmul_rn(qz,qz));

  float dl[16]; int il[16];
  #pragma unroll
  for (int u=0;u<16;u++){ dl[u]=INFINITY; il[u]=-1; }
  float maxd = INFINITY; int maxslot = 0;

  int c0 = s*CAND;
  for (int tb=0; tb<CAND; tb+=256){
    int p = c0 + tb + threadIdx.x;
    float px = Ppb[p], py = Ppb[Np+p], pz = Ppb[2*Np+p];
    float pp = __fadd_rn(__fadd_rn(__fmul_rn(px,px),__fmul_rn(py,py)),__fmul_rn(pz,pz));
    __syncthreads();
    tile[threadIdx.x] = make_float4(px,py,pz,pp);
    __syncthreads();
    for (int j=0;j<256;j++){
      float4 c = tile[j];
      float dot = __fadd_rn(__fadd_rn(__fmul_rn(qx,c.x),__fmul_rn(qy,c.y)),__fmul_rn(qz,c.z));
      float dc  = __fsub_rn(__fadd_rn(qq,c.w), __fmul_rn(2.0f,dot));
      if (dc < maxd){
        int pidx = c0 + tb + j;
        #pragma unroll
        for (int u=0;u<16;u++){ bool sel=(maxslot==u); dl[u]=sel?dc:dl[u]; il[u]=sel?pidx:il[u]; }
        maxd = dl[0]; maxslot = 0;
        #pragma unroll
        for (int u=1;u<16;u++){ bool g=(dl[u]>maxd); maxd=g?dl[u]:maxd; maxslot=g?u:maxslot; }
      }
    }
  }
  size_t base = ((size_t)qg*gridDim.y + s)*16;
  #pragma unroll
  for (int u=0;u<16;u++){ part_d[base+u]=dl[u]; part_i[base+u]=il[u]; }
}

// merge split partial lists -> final 16 (lex (d, idx) smallest)
__global__ __launch_bounds__(256) void knn_merge(const float* __restrict__ part_d,
    const int* __restrict__ part_i, int* __restrict__ idxk, int S, int total){
  int qg = blockIdx.x*256 + threadIdx.x;
  if (qg >= total) return;
  const float* pd = part_d + (size_t)qg*S*16;
  const int*   pi = part_i + (size_t)qg*S*16;
  float dl[16]; int il[16];
  #pragma unroll
  for (int u=0;u<16;u++){ dl[u]=INFINITY; il[u]=0x7fffffff; }
  float maxd = INFINITY; int maxi = 0x7fffffff; int maxslot = 0;
  int tot = S*16;
  for (int e=0;e<tot;e++){
    float d = pd[e]; int ii = pi[e];
    bool better = (d < maxd) || (d == maxd && ii < maxi);
    if (better){
      #pragma unroll
      for (int u=0;u<16;u++){ bool sel=(maxslot==u); dl[u]=sel?d:dl[u]; il[u]=sel?ii:il[u]; }
      maxd = dl[0]; maxi = il[0]; maxslot = 0;
      #pragma unroll
      for (int u=1;u<16;u++){
        bool g = (dl[u]>maxd) || (dl[u]==maxd && il[u]>maxi);
        maxd=g?dl[u]:maxd; maxi=g?il[u]:maxi; maxslot=g?u:maxslot;
      }
    }
  }
  #pragma unroll
  for (int u=0;u<16;u++) idxk[(size_t)qg*16+u] = il[u];
}

// ---------------------------------------------------------------------------
// EdgeConv pre-activation: pre[b,o,n,k] = W[o,:] . concat(Fk[:,idx]-Fi[:,n], Fi[:,n])
// thread = (k = t&15, o = t>>4 [+64]); W and pair staged in LDS (rows padded +4)
// ---------------------------------------------------------------------------
template<int CIN, int COUT>
__global__ __launch_bounds__(1024) void edge_conv_pre(
    const float* __restrict__ Fk, const float* __restrict__ Fi,
    const int* __restrict__ idx, const float* __restrict__ W,
    float* __restrict__ pre, int Nq, int Np){
  constexpr int C2  = 2*CIN;
  constexpr int PAD = C2 + 4;
  constexpr int TO  = (COUT <= 64) ? COUT : 64;
  constexpr int OP  = COUT / TO;
  extern __shared__ float sm[];
  float* Wl = sm;                 // [COUT][PAD]
  float* Pl = sm + COUT*PAD;      // [16][PAD]
  int t = threadIdx.x;
  int n = blockIdx.x, b = blockIdx.y;
  for (int e=t; e<COUT*C2; e += blockDim.x){
    int o=e/C2, c=e%C2; Wl[o*PAD+c] = W[e];
  }
  const int* idxn = idx + ((size_t)b*Nq + n)*16;
  for (int e=t; e<16*C2; e += blockDim.x){
    int k = e/C2, c = e%C2;
    int cc = (c < CIN) ? c : (c-CIN);
    float fi = Fi[((size_t)b*CIN + cc)*Nq + n];
    float v;
    if (c < CIN){ int nb = idxn[k]; v = Fk[((size_t)b*CIN + c)*Np + nb] - fi; }
    else v = fi;
    Pl[k*PAD+c] = v;
  }
  __syncthreads();
  int k = t & 15, o0 = t >> 4;
  #pragma unroll
  for (int op=0; op<OP; op++){
    int o = o0 + op*TO;
    float acc = 0.f;
    #pragma unroll
    for (int c=0;c<C2;c+=4){
      float4 wv = *(const float4*)&Wl[o*PAD+c];
      float4 pv = *(const float4*)&Pl[k*PAD+c];
      acc = fmaf(wv.x,pv.x,acc); acc = fmaf(wv.y,pv.y,acc);
      acc = fmaf(wv.z,pv.z,acc); acc = fmaf(wv.w,pv.w,acc);
    }
    pre[(((size_t)b*COUT + o)*Nq + n)*16 + k] = acc;
  }
}

// GroupNorm stats: sum/sumsq per (b,g) in double, slab contiguous in pre
__global__ __launch_bounds__(256) void gn_reduce(const float* __restrict__ pre,
    double* __restrict__ gsum, int slabLen){
  int b = blockIdx.z, g = blockIdx.y;
  size_t base = ((size_t)(b*8+g))*slabLen;
  int chunkLen = slabLen / gridDim.x;
  const float* p = pre + base + (size_t)blockIdx.x*chunkLen;
  double s=0.0, sq=0.0;
  for (int i = threadIdx.x*4; i < chunkLen; i += 1024){
    float4 v = *(const float4*)(p+i);
    s += (double)v.x; sq = fma((double)v.x,(double)v.x,sq);
    s += (double)v.y; sq = fma((double)v.y,(double)v.y,sq);
    s += (double)v.z; sq = fma((double)v.z,(double)v.z,sq);
    s += (double)v.w; sq = fma((double)v.w,(double)v.w,sq);
  }
  #pragma unroll
  for (int off=32; off>=1; off>>=1){ s += __shfl_down(s, off); sq += __shfl_down(sq, off); }
  __shared__ double ls[4], lq[4];
  int wid = threadIdx.x>>6;
  if ((threadIdx.x&63)==0){ ls[wid]=s; lq[wid]=sq; }
  __syncthreads();
  if (threadIdx.x==0){
    double S=ls[0]+ls[1]+ls[2]+ls[3], Q=lq[0]+lq[1]+lq[2]+lq[3];
    atomicAdd(&gsum[(b*8+g)*2],   S);
    atomicAdd(&gsum[(b*8+g)*2+1], Q);
  }
}

// normalize + affine + relu + max over K -> F[b,o,n]
template<int COUT>
__global__ __launch_bounds__(256) void gn_act_max(const float* __restrict__ pre,
    const double* __restrict__ gsum, const float* __restrict__ gamma,
    const float* __restrict__ beta, float* __restrict__ outF, int Nq){
  int id = blockIdx.x*256 + threadIdx.x;           // B*COUT*Nq
  int o = (id/Nq)%COUT; int b = id/(Nq*COUT);
  int g = o/(COUT/8);
  double s = gsum[(b*8+g)*2], sq = gsum[(b*8+g)*2+1];
  double cnt = (double)(COUT/8)*Nq*16.0;
  double mu  = s/cnt;
  double var = sq/cnt - mu*mu;
  float muf=(float)mu, rstd=(float)(1.0/sqrt(var+1e-5));
  float ga=gamma[o], be=beta[o];
  const float4* p = (const float4*)(pre + (size_t)id*16);
  float m = 0.f;
  #pragma unroll
  for (int q=0;q<4;q++){
    float4 v = p[q];
    m = fmaxf(m, fmaf((v.x-muf)*rstd, ga, be));
    m = fmaxf(m, fmaf((v.y-muf)*rstd, ga, be));
    m = fmaxf(m, fmaf((v.z-muf)*rstd, ga, be));
    m = fmaxf(m, fmaf((v.w-muf)*rstd, ga, be));
  }
  outF[id] = m;
}

// ---------------------------------------------------------------------------
// FPS: 1 block per batch, 1024 threads, dists+coords in registers.
// Mirrors reference arithmetic ((p-s)^2 sums, no FMA); argmax ties -> lowest
// index via packed (dbits, ~idx) u64 keys.
// ---------------------------------------------------------------------------
template<int PPT, int M>
__global__ __launch_bounds__(1024) void fps_kernel(const float* __restrict__ P,
    int* __restrict__ idx_out){
  constexpr int N = PPT*1024;
  extern __shared__ float sm[];
  float* lx = sm; float* ly = sm+N; float* lz = sm+2*N;
  unsigned long long* wkey = (unsigned long long*)(sm + 3*N);
  int b = blockIdx.x; int t = threadIdx.x;
  const float* Pb = P + (size_t)b*3*N;
  float px[PPT], py[PPT], pz[PPT], dist[PPT];
  #pragma unroll
  for (int j=0;j<PPT;j++){
    int p=j*1024+t;
    px[j]=Pb[p]; py[j]=Pb[N+p]; pz[j]=Pb[2*N+p];
    lx[p]=px[j]; ly[p]=py[j]; lz[p]=pz[j];
  }
  __syncthreads();
  float sx=lx[0], sy=ly[0], sz=lz[0];
  #pragma unroll
  for (int j=0;j<PPT;j++){
    float dx=__fsub_rn(px[j],sx), dy=__fsub_rn(py[j],sy), dz=__fsub_rn(pz[j],sz);
    dist[j]=__fadd_rn(__fadd_rn(__fmul_rn(dx,dx),__fmul_rn(dy,dy)),__fmul_rn(dz,dz));
  }
  if (t==0) idx_out[(size_t)b*M] = 0;
  int wid = t>>6, lane = t&63;
  for (int i=1;i<M;i++){
    float bd = dist[0]; int bj = 0;
    #pragma unroll
    for (int j=1;j<PPT;j++){ bool c = dist[j] > bd; bd = c?dist[j]:bd; bj = c?j:bj; }
    unsigned int gidx = (unsigned)(bj*1024 + t);
    unsigned long long key = ((unsigned long long)__float_as_uint(bd) << 32)
                           | (unsigned long long)(0xFFFFFFFFu - gidx);
    #pragma unroll
    for (int off=32; off>=1; off>>=1){
      unsigned long long o = __shfl_xor(key, off, 64);
      key = (key > o) ? key : o;
    }
    if (lane==0) wkey[wid]=key;
    __syncthreads();
    unsigned long long best = wkey[0];
    #pragma unroll
    for (int w=1;w<16;w++){ unsigned long long o=wkey[w]; best = (best>o)?best:o; }
    unsigned int widx = 0xFFFFFFFFu - (unsigned)(best & 0xFFFFFFFFull);
    if (t==0) idx_out[(size_t)b*M + i] = (int)widx;
    float nsx = lx[widx], nsy = ly[widx], nsz = lz[widx];
    #pragma unroll
    for (int j=0;j<PPT;j++){
      float dx=__fsub_rn(px[j],nsx), dy=__fsub_rn(py[j],nsy), dz=__fsub_rn(pz[j],nsz);
      float dd=__fadd_rn(__fadd_rn(__fmul_rn(dx,dx),__fmul_rn(dy,dy)),__fmul_rn(dz,dz));
      dist[j] = fminf(dist[j], dd);
    }
    __syncthreads();
  }
}

// gather: dst[b,c,m] = src[b,c,idx[b,m]]
__global__ __launch_bounds__(256) void gather_kernel(float* __restrict__ dst,
    const float* __restrict__ src, const int* __restrict__ idx,
    int C, int Nsrc, int M){
  int id = blockIdx.x*256 + threadIdx.x;     // B*C*M
  int m = id % M; int c = (id/M)%C; int b = id/(M*C);
  dst[id] = src[((size_t)b*C + c)*Nsrc + idx[(size_t)b*M + m]];
}

// ---------------------------------------------------------------------------
extern "C" void kernel_launch(void* const* d_in, const int* in_sizes, int n_in,
                              void* d_out, int out_size, void* d_ws, size_t ws_size,
                              hipStream_t stream) {
  const float* xyz    = (const float*)d_in[0];
  const float* stem_w = (const float*)d_in[1];
  const float* stem_b = (const float*)d_in[2];
  const float* w1 = (const float*)d_in[3];
  const float* g1 = (const float*)d_in[4];
  const float* b1 = (const float*)d_in[5];
  const float* w2 = (const float*)d_in[6];
  const float* g2 = (const float*)d_in[7];
  const float* b2 = (const float*)d_in[8];
  const float* w3 = (const float*)d_in[9];
  const float* g3 = (const float*)d_in[10];
  const float* b3 = (const float*)d_in[11];
  const float* w4 = (const float*)d_in[12];
  const float* g4 = (const float*)d_in[13];
  const float* b4 = (const float*)d_in[14];

  float* out = (float*)d_out;
  float* P0o  = out + 0;        // [2,3,8192]
  float* F0a  = out + 49152;    // [2,32,8192]
  float* P1o  = out + 573440;   // [2,3,2048]
  float* F1a  = out + 585728;   // [2,64,2048]
  float* P2o  = out + 847872;   // [2,3,512]
  float* F2a  = out + 850944;   // [2,128,512]

  char* ws = (char*)d_ws;
  float* F0     = (float*)(ws + 0);                 // 2*8*8192
  float* pre    = (float*)(ws + 524288);            // up to 2*32*8192*16 f32 (33.5MB)
  float* part_d = (float*)(ws + 524288);            // aliases pre (used before pre writes)
  int*   part_i = (int*)  (ws + 524288 + 8388608);
  int*   idxk   = (int*)  (ws + 34078720);          // up to 2*8192*16
  double* gsum  = (double*)(ws + 35127296);         // 16*(sum,sumsq)
  int*   idx1   = (int*)  (ws + 35127552);          // 2*2048
  int*   idx2   = (int*)  (ws + 35143936);          // 2*512
  float* F1sk   = (float*)(ws + 35148032);          // 2*32*2048
  float* F2sk   = (float*)(ws + 35672320);          // 2*64*512
  float* F2mid  = (float*)(ws + 35934464);          // 2*64*512

  size_t smem_c1 = (size_t)(32*20  + 16*20 )*4;
  size_t smem_c2 = (size_t)(64*132 + 16*132)*4;
  size_t smem_c4 = (size_t)(128*132+ 16*132)*4;
  size_t smem_f1 = (size_t)3*8192*4 + 128;
  size_t smem_f2 = (size_t)3*2048*4 + 128;

  // P0 passthrough
  hipMemcpyAsync(P0o, xyz, (size_t)49152*4, hipMemcpyDeviceToDevice, stream);
  // stem
  stem_kernel<<<(2*8192)/256, 256, 0, stream>>>(xyz, stem_w, stem_b, F0, 8192);

  // ---- stage 1: EdgeConv(F0,F0,P0,P0) -> F0a [2,32,8192]
  knn_kernel<<<dim3(16384/256, 8), 256, 0, stream>>>(xyz, xyz, part_d, part_i, 8192, 8192, 1024);
  knn_merge <<<16384/256, 256, 0, stream>>>(part_d, part_i, idxk, 8, 16384);
  edge_conv_pre<8,32><<<dim3(8192,2), 512, smem_c1, stream>>>(F0, F0, idxk, w1, pre, 8192, 8192);
  hipMemsetAsync(gsum, 0, 256, stream);
  gn_reduce<<<dim3(8,8,2), 256, 0, stream>>>(pre, gsum, 4*8192*16);
  gn_act_max<32><<<(2*32*8192)/256, 256, 0, stream>>>(pre, gsum, g1, b1, F0a, 8192);

  // ---- FPS 8192 -> 2048, gathers
  fps_kernel<8,2048><<<2, 1024, smem_f1, stream>>>(xyz, idx1);
  gather_kernel<<<(2*3*2048)/256, 256, 0, stream>>>(P1o, xyz, idx1, 3, 8192, 2048);
  gather_kernel<<<(2*32*2048)/256, 256, 0, stream>>>(F1sk, F0a, idx1, 32, 8192, 2048);

  // ---- stage 2: EdgeConv(F1sk, F0a, P1, P0) -> F1a [2,64,2048]
  knn_kernel<<<dim3(4096/256, 8), 256, 0, stream>>>(P1o, xyz, part_d, part_i, 2048, 8192, 1024);
  knn_merge <<<4096/256, 256, 0, stream>>>(part_d, part_i, idxk, 8, 4096);
  edge_conv_pre<32,64><<<dim3(2048,2), 1024, smem_c2, stream>>>(F0a, F1sk, idxk, w2, pre, 2048, 8192);
  hipMemsetAsync(gsum, 0, 256, stream);
  gn_reduce<<<dim3(4,8,2), 256, 0, stream>>>(pre, gsum, 8*2048*16);
  gn_act_max<64><<<(2*64*2048)/256, 256, 0, stream>>>(pre, gsum, g2, b2, F1a, 2048);

  // ---- FPS 2048 -> 512, gathers
  fps_kernel<2,512><<<2, 1024, smem_f2, stream>>>(P1o, idx2);
  gather_kernel<<<(2*3*512)/256, 256, 0, stream>>>(P2o, P1o, idx2, 3, 2048, 512);
  gather_kernel<<<(2*64*512)/256, 256, 0, stream>>>(F2sk, F1a, idx2, 64, 2048, 512);

  // ---- stage 3: EdgeConv(F2sk, F1a, P2, P1) -> F2mid [2,64,512]
  knn_kernel<<<dim3(1024/256, 8), 256, 0, stream>>>(P2o, P1o, part_d, part_i, 512, 2048, 256);
  knn_merge <<<1024/256, 256, 0, stream>>>(part_d, part_i, idxk, 8, 1024);
  edge_conv_pre<64,64><<<dim3(512,2), 1024, smem_c2, stream>>>(F1a, F2sk, idxk, w3, pre, 512, 2048);
  hipMemsetAsync(gsum, 0, 256, stream);
  gn_reduce<<<dim3(1,8,2), 256, 0, stream>>>(pre, gsum, 8*512*16);
  gn_act_max<64><<<(2*64*512)/256, 256, 0, stream>>>(pre, gsum, g3, b3, F2mid, 512);

  // ---- stage 4: EdgeConv(F2mid, F1a, P2, P1) -> F2a [2,128,512]  (same knn idx)
  edge_conv_pre<64,128><<<dim3(512,2), 1024, smem_c4, stream>>>(F1a, F2mid, idxk, w4, pre, 512, 2048);
  hipMemsetAsync(gsum, 0, 256, stream);
  gn_reduce<<<dim3(2,8,2), 256, 0, stream>>>(pre, gsum, 16*512*16);
  gn_act_max<128><<<(2*128*512)/256, 256, 0, stream>>>(pre, gsum, g4, b4, F2a, 512);

  (void)in_sizes; (void)n_in; (void)out_size; (void)ws_size;
}

// Round 2
// 4044.092 us; speedup vs baseline: 1.3945x; 1.3945x over previous
//
#include <hip/hip_runtime.h>
#include <math.h>

#define KNN 16

// ---------------------------------------------------------------------------
// stem: F0[b,o,n] = stem_w[o,:] . xyz[b,:,n] + stem_b[o]   (B=2, C=8, N=8192)
// ---------------------------------------------------------------------------
__global__ __launch_bounds__(256) void stem_kernel(const float* __restrict__ xyz,
    const float* __restrict__ w, const float* __restrict__ bias,
    float* __restrict__ F0, int N){
  int id = blockIdx.x*256 + threadIdx.x;          // B*N
  int n = id % N; int b = id / N;
  float x = xyz[((size_t)b*3+0)*N+n];
  float y = xyz[((size_t)b*3+1)*N+n];
  float z = xyz[((size_t)b*3+2)*N+n];
  #pragma unroll
  for (int o=0;o<8;o++){
    float v = fmaf(w[o*3+0],x, fmaf(w[o*3+1],y, fmaf(w[o*3+2],z, bias[o])));
    F0[((size_t)b*8+o)*N+n] = v;
  }
}

// ---------------------------------------------------------------------------
// KNN: per-thread top-16 (smallest d), split over gridDim.y candidate ranges.
// Distance mirrors reference: (qq + pp) - 2*dot, all non-contracted IEEE ops.
// CAND must be a multiple of 256.
// ---------------------------------------------------------------------------
__global__ __launch_bounds__(256) void knn_kernel(
    const float* __restrict__ Pq, const float* __restrict__ Pp,
    float* __restrict__ part_d, int* __restrict__ part_i,
    int Nq, int Np, int CAND){
  __shared__ float4 tile[256];
  int qg = blockIdx.x*256 + threadIdx.x;
  int b  = qg / Nq, qn = qg % Nq;
  int s  = blockIdx.y;
  const float* Pqb = Pq + (size_t)b*3*Nq;
  const float* Ppb = Pp + (size_t)b*3*Np;
  float qx = Pqb[qn], qy = Pqb[Nq+qn], qz = Pqb[2*Nq+qn];
  float qq = __fadd_rn(__fadd_rn(__fmul_rn(qx,qx),__fmul_rn(qy,qy)),__fmul_rn(qz,qz));

  float dl[16]; int il[16];
  #pragma unroll
  for (int u=0;u<16;u++){ dl[u]=INFINITY; il[u]=-1; }
  float maxd = INFINITY; int maxslot = 0;

  int c0 = s*CAND;
  for (int tb=0; tb<CAND; tb+=256){
    int p = c0 + tb + threadIdx.x;
    float px = Ppb[p], py = Ppb[Np+p], pz = Ppb[2*Np+p];
    float pp = __fadd_rn(__fadd_rn(__fmul_rn(px,px),__fmul_rn(py,py)),__fmul_rn(pz,pz));
    __syncthreads();
    tile[threadIdx.x] = make_float4(px,py,pz,pp);
    __syncthreads();
    for (int j=0;j<256;j++){
      float4 c = tile[j];
      float dot = __fadd_rn(__fadd_rn(__fmul_rn(qx,c.x),__fmul_rn(qy,c.y)),__fmul_rn(qz,c.z));
      float dc  = __fsub_rn(__fadd_rn(qq,c.w), __fmul_rn(2.0f,dot));
      if (dc < maxd){
        int pidx = c0 + tb + j;
        #pragma unroll
        for (int u=0;u<16;u++){ bool sel=(maxslot==u); dl[u]=sel?dc:dl[u]; il[u]=sel?pidx:il[u]; }
        maxd = dl[0]; maxslot = 0;
        #pragma unroll
        for (int u=1;u<16;u++){ bool g=(dl[u]>maxd); maxd=g?dl[u]:maxd; maxslot=g?u:maxslot; }
      }
    }
  }
  size_t base = ((size_t)qg*gridDim.y + s)*16;
  #pragma unroll
  for (int u=0;u<16;u++){ part_d[base+u]=dl[u]; part_i[base+u]=il[u]; }
}

// merge split partial lists -> final 16 (lex (d, idx) smallest)
__global__ __launch_bounds__(256) void knn_merge(const float* __restrict__ part_d,
    const int* __restrict__ part_i, int* __restrict__ idxk, int S, int total){
  int qg = blockIdx.x*256 + threadIdx.x;
  if (qg >= total) return;
  const float* pd = part_d + (size_t)qg*S*16;
  const int*   pi = part_i + (size_t)qg*S*16;
  float dl[16]; int il[16];
  #pragma unroll
  for (int u=0;u<16;u++){ dl[u]=INFINITY; il[u]=0x7fffffff; }
  float maxd = INFINITY; int maxi = 0x7fffffff; int maxslot = 0;
  int tot = S*16;
  for (int e=0;e<tot;e++){
    float d = pd[e]; int ii = pi[e];
    bool better = (d < maxd) || (d == maxd && ii < maxi);
    if (better){
      #pragma unroll
      for (int u=0;u<16;u++){ bool sel=(maxslot==u); dl[u]=sel?d:dl[u]; il[u]=sel?ii:il[u]; }
      maxd = dl[0]; maxi = il[0]; maxslot = 0;
      #pragma unroll
      for (int u=1;u<16;u++){
        bool g = (dl[u]>maxd) || (dl[u]==maxd && il[u]>maxi);
        maxd=g?dl[u]:maxd; maxi=g?il[u]:maxi; maxslot=g?u:maxslot;
      }
    }
  }
  #pragma unroll
  for (int u=0;u<16;u++) idxk[(size_t)qg*16+u] = il[u];
}

// ---------------------------------------------------------------------------
// EdgeConv pre-activation: pre[b,o,n,k] = W[o,:] . concat(Fk[:,idx]-Fi[:,n], Fi[:,n])
// ---------------------------------------------------------------------------
template<int CIN, int COUT>
__global__ __launch_bounds__(1024) void edge_conv_pre(
    const float* __restrict__ Fk, const float* __restrict__ Fi,
    const int* __restrict__ idx, const float* __restrict__ W,
    float* __restrict__ pre, int Nq, int Np){
  constexpr int C2  = 2*CIN;
  constexpr int PAD = C2 + 4;
  constexpr int TO  = (COUT <= 64) ? COUT : 64;
  constexpr int OP  = COUT / TO;
  extern __shared__ float sm[];
  float* Wl = sm;                 // [COUT][PAD]
  float* Pl = sm + COUT*PAD;      // [16][PAD]
  int t = threadIdx.x;
  int n = blockIdx.x, b = blockIdx.y;
  for (int e=t; e<COUT*C2; e += blockDim.x){
    int o=e/C2, c=e%C2; Wl[o*PAD+c] = W[e];
  }
  const int* idxn = idx + ((size_t)b*Nq + n)*16;
  for (int e=t; e<16*C2; e += blockDim.x){
    int k = e/C2, c = e%C2;
    int cc = (c < CIN) ? c : (c-CIN);
    float fi = Fi[((size_t)b*CIN + cc)*Nq + n];
    float v;
    if (c < CIN){ int nb = idxn[k]; v = Fk[((size_t)b*CIN + c)*Np + nb] - fi; }
    else v = fi;
    Pl[k*PAD+c] = v;
  }
  __syncthreads();
  int k = t & 15, o0 = t >> 4;
  #pragma unroll
  for (int op=0; op<OP; op++){
    int o = o0 + op*TO;
    float acc = 0.f;
    #pragma unroll
    for (int c=0;c<C2;c+=4){
      float4 wv = *(const float4*)&Wl[o*PAD+c];
      float4 pv = *(const float4*)&Pl[k*PAD+c];
      acc = fmaf(wv.x,pv.x,acc); acc = fmaf(wv.y,pv.y,acc);
      acc = fmaf(wv.z,pv.z,acc); acc = fmaf(wv.w,pv.w,acc);
    }
    pre[(((size_t)b*COUT + o)*Nq + n)*16 + k] = acc;
  }
}

// GroupNorm stats: sum/sumsq per (b,g) in double, slab contiguous in pre
__global__ __launch_bounds__(256) void gn_reduce(const float* __restrict__ pre,
    double* __restrict__ gsum, int slabLen){
  int b = blockIdx.z, g = blockIdx.y;
  size_t base = ((size_t)(b*8+g))*slabLen;
  int chunkLen = slabLen / gridDim.x;
  const float* p = pre + base + (size_t)blockIdx.x*chunkLen;
  double s=0.0, sq=0.0;
  for (int i = threadIdx.x*4; i < chunkLen; i += 1024){
    float4 v = *(const float4*)(p+i);
    s += (double)v.x; sq = fma((double)v.x,(double)v.x,sq);
    s += (double)v.y; sq = fma((double)v.y,(double)v.y,sq);
    s += (double)v.z; sq = fma((double)v.z,(double)v.z,sq);
    s += (double)v.w; sq = fma((double)v.w,(double)v.w,sq);
  }
  #pragma unroll
  for (int off=32; off>=1; off>>=1){ s += __shfl_down(s, off); sq += __shfl_down(sq, off); }
  __shared__ double ls[4], lq[4];
  int wid = threadIdx.x>>6;
  if ((threadIdx.x&63)==0){ ls[wid]=s; lq[wid]=sq; }
  __syncthreads();
  if (threadIdx.x==0){
    double S=ls[0]+ls[1]+ls[2]+ls[3], Q=lq[0]+lq[1]+lq[2]+lq[3];
    atomicAdd(&gsum[(b*8+g)*2],   S);
    atomicAdd(&gsum[(b*8+g)*2+1], Q);
  }
}

// normalize + affine + relu + max over K -> F[b,o,n]
template<int COUT>
__global__ __launch_bounds__(256) void gn_act_max(const float* __restrict__ pre,
    const double* __restrict__ gsum, const float* __restrict__ gamma,
    const float* __restrict__ beta, float* __restrict__ outF, int Nq){
  int id = blockIdx.x*256 + threadIdx.x;           // B*COUT*Nq
  int o = (id/Nq)%COUT; int b = id/(Nq*COUT);
  int g = o/(COUT/8);
  double s = gsum[(b*8+g)*2], sq = gsum[(b*8+g)*2+1];
  double cnt = (double)(COUT/8)*Nq*16.0;
  double mu  = s/cnt;
  double var = sq/cnt - mu*mu;
  float muf=(float)mu, rstd=(float)(1.0/sqrt(var+1e-5));
  float ga=gamma[o], be=beta[o];
  const float4* p = (const float4*)(pre + (size_t)id*16);
  float m = 0.f;
  #pragma unroll
  for (int q=0;q<4;q++){
    float4 v = p[q];
    m = fmaxf(m, fmaf((v.x-muf)*rstd, ga, be));
    m = fmaxf(m, fmaf((v.y-muf)*rstd, ga, be));
    m = fmaxf(m, fmaf((v.z-muf)*rstd, ga, be));
    m = fmaxf(m, fmaf((v.w-muf)*rstd, ga, be));
  }
  outF[id] = m;
}

// ---------------------------------------------------------------------------
// FPS v2: contiguous point-per-thread ownership; DPP wave argmax + ballot
// tie-break (lowest global index, matching jnp.argmax); single barrier per
// iteration via double-buffered wave keys. Exact reference arithmetic
// (non-contracted mul/add, fminf).
// ---------------------------------------------------------------------------
template<int CTRL>
__device__ __forceinline__ float dpp_maxf(float x){
  int y = __builtin_amdgcn_update_dpp(0, __float_as_int(x), CTRL, 0xf, 0xf, true);
  return fmaxf(x, __int_as_float(y));
}

template<int PPT, int BLK, int M>
__global__ __launch_bounds__(BLK) void fps_kernel(const float* __restrict__ P,
    int* __restrict__ idx_out){
  constexpr int N  = PPT*BLK;
  constexpr int NW = BLK/64;
  extern __shared__ __align__(16) float sm[];
  float* lx = sm; float* ly = sm+N; float* lz = sm+2*N;
  unsigned long long* wkey = (unsigned long long*)(sm + 3*N);
  int b = blockIdx.x, t = threadIdx.x;
  const float* Pb = P + (size_t)b*3*N;
  float px[PPT], py[PPT], pz[PPT], dist[PPT];
  #pragma unroll
  for (int j=0;j<PPT;j+=4){
    int p = t*PPT + j;
    float4 vx = *(const float4*)&Pb[p];
    float4 vy = *(const float4*)&Pb[N+p];
    float4 vz = *(const float4*)&Pb[2*N+p];
    px[j]=vx.x; px[j+1]=vx.y; px[j+2]=vx.z; px[j+3]=vx.w;
    py[j]=vy.x; py[j+1]=vy.y; py[j+2]=vy.z; py[j+3]=vy.w;
    pz[j]=vz.x; pz[j+1]=vz.y; pz[j+2]=vz.z; pz[j+3]=vz.w;
    #pragma unroll
    for (int u=0;u<4;u++){ lx[p+u]=px[j+u]; ly[p+u]=py[j+u]; lz[p+u]=pz[j+u]; }
  }
  __syncthreads();
  float sx=lx[0], sy=ly[0], sz=lz[0];
  float bd = -1.f; int bj = 0;
  #pragma unroll
  for (int j=0;j<PPT;j++){
    float dx=__fsub_rn(px[j],sx), dy=__fsub_rn(py[j],sy), dz=__fsub_rn(pz[j],sz);
    float dd=__fadd_rn(__fadd_rn(__fmul_rn(dx,dx),__fmul_rn(dy,dy)),__fmul_rn(dz,dz));
    dist[j]=dd;
    bool c = dd > bd; bd = c?dd:bd; bj = c?j:bj;
  }
  int pbest = t*PPT + bj;
  if (t==0) idx_out[(size_t)b*M] = 0;
  int wid = t>>6, lane = t&63;
  int par = 0;
  for (int i=1;i<M;i++){
    // wave-level max via DPP chain (result lands in lane 63)
    float r = bd;
    r = dpp_maxf<0x111>(r);   // row_shr:1
    r = dpp_maxf<0x112>(r);   // row_shr:2
    r = dpp_maxf<0x114>(r);   // row_shr:4
    r = dpp_maxf<0x118>(r);   // row_shr:8
    r = dpp_maxf<0x142>(r);   // row_bcast:15
    r = dpp_maxf<0x143>(r);   // row_bcast:31
    float wmax = __int_as_float(__builtin_amdgcn_readlane(__float_as_int(r), 63));
    unsigned long long msk = __ballot(bd == wmax);
    int srcl = __ffsll(msk) - 1;           // lowest lane => lowest global index
    int wp = __builtin_amdgcn_readlane(pbest, srcl);
    if (lane==0)
      wkey[par*NW + wid] = ((unsigned long long)__float_as_uint(wmax)<<32)
                         | (unsigned)(~(unsigned)wp);
    __syncthreads();
    unsigned long long best = wkey[par*NW];
    #pragma unroll
    for (int w=1;w<NW;w++){ unsigned long long o = wkey[par*NW+w]; best = (o>best)?o:best; }
    unsigned widx = ~(unsigned)best;
    if (t==0) idx_out[(size_t)b*M + i] = (int)widx;
    float nsx = lx[widx], nsy = ly[widx], nsz = lz[widx];
    par ^= 1;
    float nbd = -1.f; int nbj = 0;
    #pragma unroll
    for (int j=0;j<PPT;j++){
      float dx=__fsub_rn(px[j],nsx), dy=__fsub_rn(py[j],nsy), dz=__fsub_rn(pz[j],nsz);
      float dd=__fadd_rn(__fadd_rn(__fmul_rn(dx,dx),__fmul_rn(dy,dy)),__fmul_rn(dz,dz));
      float nd = fminf(dist[j], dd);
      dist[j] = nd;
      bool c = nd > nbd; nbd = c?nd:nbd; nbj = c?j:nbj;
    }
    bd = nbd; pbest = t*PPT + nbj;
  }
}

// gather: dst[b,c,m] = src[b,c,idx[b,m]]
__global__ __launch_bounds__(256) void gather_kernel(float* __restrict__ dst,
    const float* __restrict__ src, const int* __restrict__ idx,
    int C, int Nsrc, int M){
  int id = blockIdx.x*256 + threadIdx.x;     // B*C*M
  int m = id % M; int c = (id/M)%C; int b = id/(M*C);
  dst[id] = src[((size_t)b*C + c)*Nsrc + idx[(size_t)b*M + m]];
}

// ---------------------------------------------------------------------------
extern "C" void kernel_launch(void* const* d_in, const int* in_sizes, int n_in,
                              void* d_out, int out_size, void* d_ws, size_t ws_size,
                              hipStream_t stream) {
  const float* xyz    = (const float*)d_in[0];
  const float* stem_w = (const float*)d_in[1];
  const float* stem_b = (const float*)d_in[2];
  const float* w1 = (const float*)d_in[3];
  const float* g1 = (const float*)d_in[4];
  const float* b1 = (const float*)d_in[5];
  const float* w2 = (const float*)d_in[6];
  const float* g2 = (const float*)d_in[7];
  const float* b2 = (const float*)d_in[8];
  const float* w3 = (const float*)d_in[9];
  const float* g3 = (const float*)d_in[10];
  const float* b3 = (const float*)d_in[11];
  const float* w4 = (const float*)d_in[12];
  const float* g4 = (const float*)d_in[13];
  const float* b4 = (const float*)d_in[14];

  float* out = (float*)d_out;
  float* P0o  = out + 0;        // [2,3,8192]
  float* F0a  = out + 49152;    // [2,32,8192]
  float* P1o  = out + 573440;   // [2,3,2048]
  float* F1a  = out + 585728;   // [2,64,2048]
  float* P2o  = out + 847872;   // [2,3,512]
  float* F2a  = out + 850944;   // [2,128,512]

  char* ws = (char*)d_ws;
  float* F0     = (float*)(ws + 0);                 // 2*8*8192
  float* pre    = (float*)(ws + 524288);            // up to 33.55MB
  float* part_d = (float*)(ws + 524288);            // aliases pre (used before pre)
  int*   part_i = (int*)  (ws + 524288 + 16777216); // S=16 worst case
  int*   idxk   = (int*)  (ws + 34078720);          // up to 2*8192*16
  double* gsum  = (double*)(ws + 35127296);         // 16*(sum,sumsq)
  int*   idx1   = (int*)  (ws + 35127552);          // 2*2048
  int*   idx2   = (int*)  (ws + 35143936);          // 2*512
  float* F1sk   = (float*)(ws + 35148032);          // 2*32*2048
  float* F2sk   = (float*)(ws + 35672320);          // 2*64*512
  float* F2mid  = (float*)(ws + 35934464);          // 2*64*512

  size_t smem_c1 = (size_t)(32*20  + 16*20 )*4;
  size_t smem_c2 = (size_t)(64*132 + 16*132)*4;
  size_t smem_c4 = (size_t)(128*132+ 16*132)*4;
  size_t smem_f1 = (size_t)3*8192*4 + 256;
  size_t smem_f2 = (size_t)3*2048*4 + 256;

  // P0 passthrough
  hipMemcpyAsync(P0o, xyz, (size_t)49152*4, hipMemcpyDeviceToDevice, stream);
  // stem
  stem_kernel<<<(2*8192)/256, 256, 0, stream>>>(xyz, stem_w, stem_b, F0, 8192);

  // ---- stage 1: EdgeConv(F0,F0,P0,P0) -> F0a [2,32,8192]
  knn_kernel<<<dim3(16384/256, 16), 256, 0, stream>>>(xyz, xyz, part_d, part_i, 8192, 8192, 512);
  knn_merge <<<16384/256, 256, 0, stream>>>(part_d, part_i, idxk, 16, 16384);
  edge_conv_pre<8,32><<<dim3(8192,2), 512, smem_c1, stream>>>(F0, F0, idxk, w1, pre, 8192, 8192);
  hipMemsetAsync(gsum, 0, 256, stream);
  gn_reduce<<<dim3(8,8,2), 256, 0, stream>>>(pre, gsum, 4*8192*16);
  gn_act_max<32><<<(2*32*8192)/256, 256, 0, stream>>>(pre, gsum, g1, b1, F0a, 8192);

  // ---- FPS 8192 -> 2048, gathers
  fps_kernel<16,512,2048><<<2, 512, smem_f1, stream>>>(xyz, idx1);
  gather_kernel<<<(2*3*2048)/256, 256, 0, stream>>>(P1o, xyz, idx1, 3, 8192, 2048);
  gather_kernel<<<(2*32*2048)/256, 256, 0, stream>>>(F1sk, F0a, idx1, 32, 8192, 2048);

  // ---- stage 2: EdgeConv(F1sk, F0a, P1, P0) -> F1a [2,64,2048]
  knn_kernel<<<dim3(4096/256, 16), 256, 0, stream>>>(P1o, xyz, part_d, part_i, 2048, 8192, 512);
  knn_merge <<<4096/256, 256, 0, stream>>>(part_d, part_i, idxk, 16, 4096);
  edge_conv_pre<32,64><<<dim3(2048,2), 1024, smem_c2, stream>>>(F0a, F1sk, idxk, w2, pre, 2048, 8192);
  hipMemsetAsync(gsum, 0, 256, stream);
  gn_reduce<<<dim3(4,8,2), 256, 0, stream>>>(pre, gsum, 8*2048*16);
  gn_act_max<64><<<(2*64*2048)/256, 256, 0, stream>>>(pre, gsum, g2, b2, F1a, 2048);

  // ---- FPS 2048 -> 512, gathers
  fps_kernel<4,512,512><<<2, 512, smem_f2, stream>>>(P1o, idx2);
  gather_kernel<<<(2*3*512)/256, 256, 0, stream>>>(P2o, P1o, idx2, 3, 2048, 512);
  gather_kernel<<<(2*64*512)/256, 256, 0, stream>>>(F2sk, F1a, idx2, 64, 2048, 512);

  // ---- stage 3: EdgeConv(F2sk, F1a, P2, P1) -> F2mid [2,64,512]
  knn_kernel<<<dim3(1024/256, 8), 256, 0, stream>>>(P2o, P1o, part_d, part_i, 512, 2048, 256);
  knn_merge <<<1024/256, 256, 0, stream>>>(part_d, part_i, idxk, 8, 1024);
  edge_conv_pre<64,64><<<dim3(512,2), 1024, smem_c2, stream>>>(F1a, F2sk, idxk, w3, pre, 512, 2048);
  hipMemsetAsync(gsum, 0, 256, stream);
  gn_reduce<<<dim3(1,8,2), 256, 0, stream>>>(pre, gsum, 8*512*16);
  gn_act_max<64><<<(2*64*512)/256, 256, 0, stream>>>(pre, gsum, g3, b3, F2mid, 512);

  // ---- stage 4: EdgeConv(F2mid, F1a, P2, P1) -> F2a [2,128,512]  (same knn idx)
  edge_conv_pre<64,128><<<dim3(512,2), 1024, smem_c4, stream>>>(F1a, F2mid, idxk, w4, pre, 512, 2048);
  hipMemsetAsync(gsum, 0, 256, stream);
  gn_reduce<<<dim3(2,8,2), 256, 0, stream>>>(pre, gsum, 16*512*16);
  gn_act_max<128><<<(2*128*512)/256, 256, 0, stream>>>(pre, gsum, g4, b4, F2a, 512);

  (void)in_sizes; (void)n_in; (void)out_size; (void)ws_size;
}